// Round 12
// baseline (69.963 us; speedup 1.0000x reference)
//
#include <hip/hip_runtime.h>

#define EPS 1e-6f

// C2 = FIXED_T/(NUM_LEVELS-1) * log2(e) = 100/(15*ln2);  g = 2^-C2 = exp(-100/15)
static constexpr float C2  = 9.617966939259756f;
static constexpr float GC  = 1.2742546176474651e-3f;  // g/(1-g)
static constexpr float C3  = 0.9987273661986602f;     // 1-g
static constexpr float D1  = 511.0f * C3;             // deposit scale (max 510)

typedef float floatx4 __attribute__((ext_vector_type(4)));

#if __has_builtin(__builtin_amdgcn_exp2f)
__device__ __forceinline__ float fast_exp2(float x) { return __builtin_amdgcn_exp2f(x); }
#else
__device__ __forceinline__ float fast_exp2(float x) { return exp2f(x); }
#endif

#if __has_builtin(__builtin_amdgcn_rcpf)
__device__ __forceinline__ float fast_rcp(float x) { return __builtin_amdgcn_rcpf(x); }
#else
__device__ __forceinline__ float fast_rcp(float x) { return 1.0f / x; }
#endif

// deterministic block-wide sum for 512 threads (8 waves); red has 8 floats/slot
__device__ __forceinline__ float block_sum_512(float v, float* red, int slot) {
    #pragma unroll
    for (int o = 32; o > 0; o >>= 1) v += __shfl_xor(v, o, 64);
    const int t = threadIdx.x;
    __syncthreads();  // protect prior use of red
    if ((t & 63) == 0) red[slot * 8 + (t >> 6)] = v;
    __syncthreads();
    float s = 0.0f;
    #pragma unroll
    for (int wv = 0; wv < 8; ++wv) s += red[slot * 8 + wv];
    return s;
}

__global__ __launch_bounds__(512, 8) void bq_main_kernel(
    const float* __restrict__ weight,
    const float* __restrict__ w_min,
    const float* __restrict__ w_max,
    float* __restrict__ out,
    float* __restrict__ ent_partial,
    unsigned int* __restrict__ done_cnt,
    float* __restrict__ out_ent)
{
    // bins[n*128 + slot], slot(col) = 32*(col&3) + (col>>2).
    // bank = slot&31 = cq -> distinct per 32-lane half; lanes L/L+32 share an
    // address but a wave64 LDS op is >=2 cyc anyway, so the 2-way atomic is free.
    __shared__ unsigned int bins[16 * 128];   // 8 KB
    __shared__ float red[16];
    __shared__ unsigned int is_last;

    const int bid = blockIdx.x;
    const int br = bid >> 5;
    const int bc = bid & 31;
    const int t = threadIdx.x;      // 0..511
    const int cq = t & 31;          // column quad (cols 4cq..4cq+3)
    const int rg = t >> 5;          // row group (16 groups x 8 rows)

    #pragma unroll
    for (int i = 0; i < 4; ++i) bins[t + i * 512] = 0u;

    // per-block scale params (reference semantics)
    const float wmn = w_min[bid];
    const float wmx = w_max[bid];
    const float lo = fminf(wmn, wmx - EPS);
    const float hi = fmaxf(wmx, lo + EPS);
    const float scale = hi - lo + EPS;
    const float s15 = 15.0f / scale;
    const float dmm15 = (hi - lo) * (1.0f / 15.0f);
    const float tb0 = -lo * s15;    // th = fmaf(w, s15, tb0) in [0,15]
    // o = nf*A1 + phi*A2 + A3  (exact 2-bin closed form; gc-term cancels
    // truncation asymmetry so interior f=0 reproduces the full ladder)
    const float A1 = dmm15;
    const float A2 = dmm15 * (1.0f + 2.0f * GC);
    const float A3 = lo - GC * dmm15;

    __syncthreads();

    const size_t base = (size_t)(br * 128 + rg * 8) * 4096 + (size_t)(bc * 128 + cq * 4);
    const floatx4* __restrict__ wp = (const floatx4*)(weight + base);
    floatx4* __restrict__ op = (floatx4*)(out + base);

    // ---- issue ALL 8 loads back-to-back; the asm pin consumes them so the
    // compiler cannot sink/serialize them: one vmcnt latency exposure total ----
    floatx4 w[8];
    #pragma unroll
    for (int i = 0; i < 8; ++i) w[i] = wp[(size_t)i * 1024];
    asm volatile("" : "+v"(w[0]), "+v"(w[1]), "+v"(w[2]), "+v"(w[3]),
                      "+v"(w[4]), "+v"(w[5]), "+v"(w[6]), "+v"(w[7]));

    // K literal -> static extracts, compile-time LDS sub-offsets, no divergence
    #define PROC(I, K) do {                                                     \
        const float th = fmaf(w[I][K], s15, tb0);                               \
        const float nf = fminf(fmaxf(floorf(th), 0.0f), 15.0f);                 \
        const int   n  = (int)nf;                                               \
        const float f  = th - nf;                                               \
        const float z  = fast_exp2(fmaf(-2.0f * C2, f, C2));  /* g^(2f-1) */    \
        const float phi = fast_rcp(1.0f + z);                 /* re/(qe+re) */  \
        o4[K] = fmaf(nf, A1, fmaf(phi, A2, A3));                                \
        const unsigned int vi = (unsigned int)fmaf(phi, D1, 0.5f);              \
        atomicAdd(&bins[n * 128 + (K << 5) + cq], vi * 65535u + 510u);          \
    } while (0)

    #pragma unroll
    for (int i = 0; i < 8; ++i) {
        floatx4 o4;
        PROC(i, 0); PROC(i, 1); PROC(i, 2); PROC(i, 3);
        __builtin_nontemporal_store(o4, &op[(size_t)i * 1024]);
    }
    #undef PROC

    __syncthreads();

    // epilogue: bin[j] = lo16(slot j) + hi16(slot j-1) per column-slot
    float s_local = 0.0f, ent = 0.0f;
    float bin[16];
    if (t < 128) {
        unsigned int prev = 0u;
        #pragma unroll
        for (int j = 0; j < 16; ++j) {
            const unsigned int cur = bins[j * 128 + t];
            bin[j] = (float)((cur & 0xFFFFu) + (prev >> 16));
            prev = cur;
            s_local += bin[j];
        }
    }

    const float B = block_sum_512(s_local, red, 0);
    const float invB = fast_rcp(B + EPS);

    if (t < 128) {
        #pragma unroll
        for (int j = 0; j < 16; ++j) {
            const float p = bin[j] * invB;
            ent = fmaf(p, __logf(p + EPS), ent);
        }
    }
    const float entB = block_sum_512(ent, red, 1);

    // ---- last-block entropy fold (saves the 2nd launch) ----
    if (t == 0) {
        ent_partial[bid] = -entB;
        __threadfence();                       // partial visible device-wide
        const unsigned int prev = atomicAdd(done_cnt, 1u);
        is_last = (prev == 1023u) ? 1u : 0u;
    }
    __syncthreads();
    if (is_last) {
        __threadfence();                       // acquire: see all partials
        if (t < 64) {
            float v = 0.0f;
            #pragma unroll
            for (int i2 = 0; i2 < 16; ++i2) v += ent_partial[t + i2 * 64];
            #pragma unroll
            for (int o = 32; o > 0; o >>= 1) v += __shfl_xor(v, o, 64);
            if (t == 0) out_ent[0] = v;        // fixed-order sum: deterministic
        }
    }
}

extern "C" void kernel_launch(void* const* d_in, const int* in_sizes, int n_in,
                              void* d_out, int out_size, void* d_ws, size_t ws_size,
                              hipStream_t stream) {
    const float* weight = (const float*)d_in[0];
    const float* wmin = (const float*)d_in[1];
    const float* wmax = (const float*)d_in[2];
    float* out = (float*)d_out;
    float* part = (float*)d_ws;                                // 1024 floats
    unsigned int* cnt = (unsigned int*)((char*)d_ws + 4096);   // done counter

    hipMemsetAsync(cnt, 0, sizeof(unsigned int), stream);      // graph-legal
    bq_main_kernel<<<1024, 512, 0, stream>>>(weight, wmin, wmax, out, part,
                                             cnt, out + (out_size - 1));
}

// Round 13
// 66.698 us; speedup vs baseline: 1.0489x; 1.0489x over previous
//
#include <hip/hip_runtime.h>

#define EPS 1e-6f

// C2 = FIXED_T/(NUM_LEVELS-1) * log2(e) = 100/(15*ln2);  g = 2^-C2 = exp(-100/15)
static constexpr float C2  = 9.617966939259756f;
static constexpr float GC  = 1.2742546176474651e-3f;  // g/(1-g)
static constexpr float C3  = 0.9987273661986602f;     // 1-g
static constexpr float D1  = 511.0f * C3;             // deposit scale (max 510)

typedef float floatx4 __attribute__((ext_vector_type(4)));

#if __has_builtin(__builtin_amdgcn_exp2f)
__device__ __forceinline__ float fast_exp2(float x) { return __builtin_amdgcn_exp2f(x); }
#else
__device__ __forceinline__ float fast_exp2(float x) { return exp2f(x); }
#endif

#if __has_builtin(__builtin_amdgcn_rcpf)
__device__ __forceinline__ float fast_rcp(float x) { return __builtin_amdgcn_rcpf(x); }
#else
__device__ __forceinline__ float fast_rcp(float x) { return 1.0f / x; }
#endif

// deterministic block-wide sum for 512 threads (8 waves); red has 8 floats/slot
__device__ __forceinline__ float block_sum_512(float v, float* red, int slot) {
    #pragma unroll
    for (int o = 32; o > 0; o >>= 1) v += __shfl_xor(v, o, 64);
    const int t = threadIdx.x;
    __syncthreads();  // protect prior use of red
    if ((t & 63) == 0) red[slot * 8 + (t >> 6)] = v;
    __syncthreads();
    float s = 0.0f;
    #pragma unroll
    for (int wv = 0; wv < 8; ++wv) s += red[slot * 8 + wv];
    return s;
}

__global__ __launch_bounds__(512, 8) void bq_main_kernel(
    const float* __restrict__ weight,
    const float* __restrict__ w_min,
    const float* __restrict__ w_max,
    float* __restrict__ out,
    float* __restrict__ ent_partial,
    unsigned int* __restrict__ done_cnt,
    float* __restrict__ out_ent)
{
    // bins[n*128 + slot], slot(col) = 32*(col&3) + (col>>2).
    // bank = slot&31 = cq -> distinct per 32-lane half; lanes L/L+32 share an
    // address but a wave64 LDS op is >=2 cyc anyway, so the 2-way atomic is free.
    __shared__ unsigned int bins[16 * 128];   // 8 KB
    __shared__ float red[16];
    __shared__ unsigned int is_last;

    const int bid = blockIdx.x;
    const int br = bid >> 5;
    const int bc = bid & 31;
    const int t = threadIdx.x;      // 0..511
    const int cq = t & 31;          // column quad (cols 4cq..4cq+3)
    const int rg = t >> 5;          // row group (16 groups x 8 rows)

    #pragma unroll
    for (int i = 0; i < 4; ++i) bins[t + i * 512] = 0u;

    // per-block scale params (reference semantics)
    const float wmn = w_min[bid];
    const float wmx = w_max[bid];
    const float lo = fminf(wmn, wmx - EPS);
    const float hi = fmaxf(wmx, lo + EPS);
    const float scale = hi - lo + EPS;
    const float s15 = 15.0f / scale;
    const float dmm15 = (hi - lo) * (1.0f / 15.0f);
    const float tb0 = -lo * s15;    // th = fmaf(w, s15, tb0) in [0,15]
    // o = nf*A1 + phi*A2 + A3  (exact 2-bin closed form; gc-term cancels
    // truncation asymmetry so interior f=0 reproduces the full ladder)
    const float A1 = dmm15;
    const float A2 = dmm15 * (1.0f + 2.0f * GC);
    const float A3 = lo - GC * dmm15;

    __syncthreads();

    const size_t base = (size_t)(br * 128 + rg * 8) * 4096 + (size_t)(bc * 128 + cq * 4);
    const floatx4* __restrict__ wp = (const floatx4*)(weight + base);
    floatx4* __restrict__ op = (floatx4*)(out + base);

    // K literal -> static extracts, compile-time LDS sub-offsets, no divergence.
    // Loads stay in-loop: the compiler's own schedule (R11) beat every manual
    // pin/prefetch attempt (R10 neutral, R12 2.9x regression).
    #define PROC(K) do {                                                        \
        const float th = fmaf(w4[K], s15, tb0);                                 \
        const float nf = fminf(fmaxf(floorf(th), 0.0f), 15.0f);                 \
        const int   n  = (int)nf;                                               \
        const float f  = th - nf;                                               \
        const float z  = fast_exp2(fmaf(-2.0f * C2, f, C2));  /* g^(2f-1) */    \
        const float phi = fast_rcp(1.0f + z);                 /* re/(qe+re) */  \
        o4[K] = fmaf(nf, A1, fmaf(phi, A2, A3));                                \
        const unsigned int vi = (unsigned int)fmaf(phi, D1, 0.5f);              \
        atomicAdd(&bins[n * 128 + (K << 5) + cq], vi * 65535u + 510u);          \
    } while (0)

    #pragma unroll
    for (int i = 0; i < 8; ++i) {
        const floatx4 w4 = wp[(size_t)i * 1024];
        floatx4 o4;
        PROC(0); PROC(1); PROC(2); PROC(3);
        __builtin_nontemporal_store(o4, &op[(size_t)i * 1024]);
    }
    #undef PROC

    __syncthreads();

    // epilogue: bin[j] = lo16(slot j) + hi16(slot j-1) per column-slot
    float s_local = 0.0f, ent = 0.0f;
    float bin[16];
    if (t < 128) {
        unsigned int prev = 0u;
        #pragma unroll
        for (int j = 0; j < 16; ++j) {
            const unsigned int cur = bins[j * 128 + t];
            bin[j] = (float)((cur & 0xFFFFu) + (prev >> 16));
            prev = cur;
            s_local += bin[j];
        }
    }

    const float B = block_sum_512(s_local, red, 0);
    const float invB = fast_rcp(B + EPS);

    if (t < 128) {
        #pragma unroll
        for (int j = 0; j < 16; ++j) {
            const float p = bin[j] * invB;
            ent = fmaf(p, __logf(p + EPS), ent);
        }
    }
    const float entB = block_sum_512(ent, red, 1);

    // ---- last-block entropy fold (replaces the 2nd launch) ----
    if (t == 0) {
        ent_partial[bid] = -entB;
        __threadfence();                       // release: partial visible
        const unsigned int prev = atomicAdd(done_cnt, 1u);
        is_last = (prev == 1023u) ? 1u : 0u;
    }
    __syncthreads();
    if (is_last) {
        __threadfence();                       // acquire: see all partials
        if (t < 64) {
            float v = 0.0f;
            #pragma unroll
            for (int i2 = 0; i2 < 16; ++i2) v += ent_partial[t + i2 * 64];
            #pragma unroll
            for (int o = 32; o > 0; o >>= 1) v += __shfl_xor(v, o, 64);
            if (t == 0) out_ent[0] = v;        // fixed-order sum: deterministic
        }
    }
}

extern "C" void kernel_launch(void* const* d_in, const int* in_sizes, int n_in,
                              void* d_out, int out_size, void* d_ws, size_t ws_size,
                              hipStream_t stream) {
    const float* weight = (const float*)d_in[0];
    const float* wmin = (const float*)d_in[1];
    const float* wmax = (const float*)d_in[2];
    float* out = (float*)d_out;
    float* part = (float*)d_ws;                                // 1024 floats
    unsigned int* cnt = (unsigned int*)((char*)d_ws + 4096);   // done counter

    hipMemsetAsync(cnt, 0, sizeof(unsigned int), stream);      // graph-legal
    bq_main_kernel<<<1024, 512, 0, stream>>>(weight, wmin, wmax, out, part,
                                             cnt, out + (out_size - 1));
}

// Round 14
// 30.141 us; speedup vs baseline: 2.3212x; 2.2128x over previous
//
#include <hip/hip_runtime.h>

#define EPS 1e-6f

// C2 = FIXED_T/(NUM_LEVELS-1) * log2(e) = 100/(15*ln2);  g = 2^-C2 = exp(-100/15)
static constexpr float C2  = 9.617966939259756f;
static constexpr float GC  = 1.2742546176474651e-3f;  // g/(1-g)
static constexpr float C3  = 0.9987273661986602f;     // 1-g
static constexpr float D1  = 511.0f * C3;             // deposit scale (max 510)

typedef float floatx4 __attribute__((ext_vector_type(4)));

#if __has_builtin(__builtin_amdgcn_exp2f)
__device__ __forceinline__ float fast_exp2(float x) { return __builtin_amdgcn_exp2f(x); }
#else
__device__ __forceinline__ float fast_exp2(float x) { return exp2f(x); }
#endif

#if __has_builtin(__builtin_amdgcn_rcpf)
__device__ __forceinline__ float fast_rcp(float x) { return __builtin_amdgcn_rcpf(x); }
#else
__device__ __forceinline__ float fast_rcp(float x) { return 1.0f / x; }
#endif

// deterministic block-wide sum for 512 threads (8 waves); red has 8 floats/slot
__device__ __forceinline__ float block_sum_512(float v, float* red, int slot) {
    #pragma unroll
    for (int o = 32; o > 0; o >>= 1) v += __shfl_xor(v, o, 64);
    const int t = threadIdx.x;
    __syncthreads();  // protect prior use of red
    if ((t & 63) == 0) red[slot * 8 + (t >> 6)] = v;
    __syncthreads();
    float s = 0.0f;
    #pragma unroll
    for (int wv = 0; wv < 8; ++wv) s += red[slot * 8 + wv];
    return s;
}

__global__ __launch_bounds__(512, 8) void bq_main_kernel(
    const float* __restrict__ weight,
    const float* __restrict__ w_min,
    const float* __restrict__ w_max,
    float* __restrict__ out,
    float* __restrict__ ent_partial)
{
    // bins[n*128 + slot], slot(col) = 32*(col&3) + (col>>2).
    // bank = slot&31 = cq -> distinct per 32-lane half; lanes L/L+32 share an
    // address but a wave64 LDS op is >=2 cyc anyway, so the 2-way atomic is free.
    __shared__ unsigned int bins[16 * 128];   // 8 KB
    __shared__ float red[16];

    const int bid = blockIdx.x;
    const int br = bid >> 5;
    const int bc = bid & 31;
    const int t = threadIdx.x;      // 0..511
    const int cq = t & 31;          // column quad (cols 4cq..4cq+3)
    const int rg = t >> 5;          // row group (16 groups x 8 rows)

    #pragma unroll
    for (int i = 0; i < 4; ++i) bins[t + i * 512] = 0u;

    // per-block scale params (reference semantics)
    const float wmn = w_min[bid];
    const float wmx = w_max[bid];
    const float lo = fminf(wmn, wmx - EPS);
    const float hi = fmaxf(wmx, lo + EPS);
    const float scale = hi - lo + EPS;
    const float s15 = 15.0f / scale;
    const float dmm15 = (hi - lo) * (1.0f / 15.0f);
    const float tb0 = -lo * s15;    // th = fmaf(w, s15, tb0) in [0,15]
    // o = nf*A1 + phi*A2 + A3  (exact 2-bin closed form; gc-term cancels
    // truncation asymmetry so interior f=0 reproduces the full ladder)
    const float A1 = dmm15;
    const float A2 = dmm15 * (1.0f + 2.0f * GC);
    const float A3 = lo - GC * dmm15;

    __syncthreads();

    const size_t base = (size_t)(br * 128 + rg * 8) * 4096 + (size_t)(bc * 128 + cq * 4);
    const floatx4* __restrict__ wp = (const floatx4*)(weight + base);
    floatx4* __restrict__ op = (floatx4*)(out + base);

    // K literal -> static extracts, compile-time LDS sub-offsets, no divergence.
    // Loads stay in-loop: compiler's own schedule beat every manual attempt
    // (R10 neutral, R12/R13 regressions). Regular stores (not NT): the 256MB
    // LLC can absorb the 66MB write set and write back asynchronously.
    #define PROC(K) do {                                                        \
        const float th = fmaf(w4[K], s15, tb0);                                 \
        const float nf = fminf(fmaxf(floorf(th), 0.0f), 15.0f);                 \
        const int   n  = (int)nf;                                               \
        const float f  = th - nf;                                               \
        const float z  = fast_exp2(fmaf(-2.0f * C2, f, C2));  /* g^(2f-1) */    \
        const float phi = fast_rcp(1.0f + z);                 /* re/(qe+re) */  \
        o4[K] = fmaf(nf, A1, fmaf(phi, A2, A3));                                \
        const unsigned int vi = (unsigned int)fmaf(phi, D1, 0.5f);              \
        atomicAdd(&bins[n * 128 + (K << 5) + cq], vi * 65535u + 510u);          \
    } while (0)

    #pragma unroll
    for (int i = 0; i < 8; ++i) {
        const floatx4 w4 = wp[(size_t)i * 1024];
        floatx4 o4;
        PROC(0); PROC(1); PROC(2); PROC(3);
        op[(size_t)i * 1024] = o4;
    }
    #undef PROC

    __syncthreads();

    // epilogue: bin[j] = lo16(slot j) + hi16(slot j-1) per column-slot
    float s_local = 0.0f, ent = 0.0f;
    float bin[16];
    if (t < 128) {
        unsigned int prev = 0u;
        #pragma unroll
        for (int j = 0; j < 16; ++j) {
            const unsigned int cur = bins[j * 128 + t];
            bin[j] = (float)((cur & 0xFFFFu) + (prev >> 16));
            prev = cur;
            s_local += bin[j];
        }
    }

    const float B = block_sum_512(s_local, red, 0);
    const float invB = fast_rcp(B + EPS);

    if (t < 128) {
        #pragma unroll
        for (int j = 0; j < 16; ++j) {
            const float p = bin[j] * invB;
            ent = fmaf(p, __logf(p + EPS), ent);
        }
    }
    const float entB = block_sum_512(ent, red, 1);
    if (t == 0) ent_partial[bid] = -entB;
}

__global__ __launch_bounds__(64) void bq_ent_reduce(
    const float* __restrict__ part, float* __restrict__ out_ent)
{
    const int t = threadIdx.x;  // 64 threads, 1024 partials
    float v = 0.0f;
    #pragma unroll
    for (int i = 0; i < 16; ++i) v += part[t + i * 64];
    #pragma unroll
    for (int o = 32; o > 0; o >>= 1) v += __shfl_xor(v, o, 64);
    if (t == 0) out_ent[0] = v;
}

extern "C" void kernel_launch(void* const* d_in, const int* in_sizes, int n_in,
                              void* d_out, int out_size, void* d_ws, size_t ws_size,
                              hipStream_t stream) {
    const float* weight = (const float*)d_in[0];
    const float* wmin = (const float*)d_in[1];
    const float* wmax = (const float*)d_in[2];
    float* out = (float*)d_out;
    float* part = (float*)d_ws;  // 1024 floats of scratch

    bq_main_kernel<<<1024, 512, 0, stream>>>(weight, wmin, wmax, out, part);
    bq_ent_reduce<<<1, 64, 0, stream>>>(part, out + (out_size - 1));
}

// Round 15
// 28.201 us; speedup vs baseline: 2.4809x; 1.0688x over previous
//
#include <hip/hip_runtime.h>

#define EPS 1e-6f

// C2 = FIXED_T/(NUM_LEVELS-1) * log2(e) = 100/(15*ln2);  g = 2^-C2 = exp(-100/15)
static constexpr float C2  = 9.617966939259756f;
static constexpr float GC  = 1.2742546176474651e-3f;  // g/(1-g)
static constexpr float C3  = 0.9987273661986602f;     // 1-g
static constexpr float D1  = 511.0f * C3;             // deposit scale (max 510)

typedef float floatx4 __attribute__((ext_vector_type(4)));

#if __has_builtin(__builtin_amdgcn_exp2f)
__device__ __forceinline__ float fast_exp2(float x) { return __builtin_amdgcn_exp2f(x); }
#else
__device__ __forceinline__ float fast_exp2(float x) { return exp2f(x); }
#endif

#if __has_builtin(__builtin_amdgcn_rcpf)
__device__ __forceinline__ float fast_rcp(float x) { return __builtin_amdgcn_rcpf(x); }
#else
__device__ __forceinline__ float fast_rcp(float x) { return 1.0f / x; }
#endif

// deterministic block-wide float2 sum for 512 threads (8 waves)
__device__ __forceinline__ float2 block_sum2_512(float2 v, float* red) {
    #pragma unroll
    for (int o = 32; o > 0; o >>= 1) {
        v.x += __shfl_xor(v.x, o, 64);
        v.y += __shfl_xor(v.y, o, 64);
    }
    const int t = threadIdx.x;
    __syncthreads();
    if ((t & 63) == 0) { red[(t >> 6)] = v.x; red[8 + (t >> 6)] = v.y; }
    __syncthreads();
    float sx = 0.0f, sy = 0.0f;
    #pragma unroll
    for (int wv = 0; wv < 8; ++wv) { sx += red[wv]; sy += red[8 + wv]; }
    return make_float2(sx, sy);
}

__global__ __launch_bounds__(512, 8) void bq_main_kernel(
    const float* __restrict__ weight,
    const float* __restrict__ w_min,
    const float* __restrict__ w_max,
    float* __restrict__ out,
    float* __restrict__ ent_partial)
{
    // bins[n*128 + slot], slot(col) = 32*(col&3) + (col>>2).
    // bank = slot&31 = cq -> distinct per 32-lane half; lanes L/L+32 share an
    // address but a wave64 LDS op is >=2 cyc anyway, so the 2-way atomic is free.
    __shared__ unsigned int bins[16 * 128];   // 8 KB
    __shared__ float red[16];

    const int bid = blockIdx.x;
    const int br = bid >> 5;
    const int bc = bid & 31;
    const int t = threadIdx.x;      // 0..511
    const int cq = t & 31;          // column quad (cols 4cq..4cq+3)
    const int rg = t >> 5;          // row group (16 groups x 8 rows)

    #pragma unroll
    for (int i = 0; i < 4; ++i) bins[t + i * 512] = 0u;

    // per-block scale params (reference semantics)
    const float wmn = w_min[bid];
    const float wmx = w_max[bid];
    const float lo = fminf(wmn, wmx - EPS);
    const float hi = fmaxf(wmx, lo + EPS);
    const float scale = hi - lo + EPS;
    const float s15 = 15.0f / scale;
    const float dmm15 = (hi - lo) * (1.0f / 15.0f);
    const float tb0 = -lo * s15;    // th = fmaf(w, s15, tb0) in [0,15]
    // o = nf*A1 + phi*A2 + A3  (exact 2-bin closed form; gc-term cancels
    // truncation asymmetry so interior f=0 reproduces the full ladder)
    const float A1 = dmm15;
    const float A2 = dmm15 * (1.0f + 2.0f * GC);
    const float A3 = lo - GC * dmm15;

    __syncthreads();

    const size_t base = (size_t)(br * 128 + rg * 8) * 4096 + (size_t)(bc * 128 + cq * 4);
    const floatx4* __restrict__ wp = (const floatx4*)(weight + base);
    floatx4* __restrict__ op = (floatx4*)(out + base);

    // K literal -> static extracts, compile-time LDS sub-offsets, no divergence
    #define PROC(K) do {                                                        \
        const float th = fmaf(cur[K], s15, tb0);                                \
        const float nf = fminf(fmaxf(floorf(th), 0.0f), 15.0f);                 \
        const int   n  = (int)nf;                                               \
        const float f  = th - nf;                                               \
        const float z  = fast_exp2(fmaf(-2.0f * C2, f, C2));  /* g^(2f-1) */    \
        const float phi = fast_rcp(1.0f + z);                 /* re/(qe+re) */  \
        o4[K] = fmaf(nf, A1, fmaf(phi, A2, A3));                                \
        const unsigned int vi = (unsigned int)fmaf(phi, D1, 0.5f);              \
        atomicAdd(&bins[n * 128 + (K << 5) + cq], vi * 65535u + 510u);          \
    } while (0)

    // rotating 2-deep register prefetch (no asm, no pin): load i+2 is issued
    // before processing i, covering LLC latency with ~2 iterations of compute.
    floatx4 cur = wp[0];
    floatx4 nx1 = wp[1024];
    #pragma unroll
    for (int i = 0; i < 8; ++i) {
        floatx4 nx2;
        if (i < 6) nx2 = wp[(size_t)(i + 2) * 1024];
        floatx4 o4;
        PROC(0); PROC(1); PROC(2); PROC(3);
        op[(size_t)i * 1024] = o4;
        cur = nx1; nx1 = nx2;
    }
    #undef PROC

    __syncthreads();

    // epilogue: bin[j] = lo16(slot j) + hi16(slot j-1) per column-slot.
    // entropy via H = ln B - (sum bin*ln bin)/B  (scale-invariant: the x510
    // fixed-point factor cancels; bin*ln(bin+1e-6) == 0 at bin == 0)
    float s_local = 0.0f, slg = 0.0f;
    if (t < 128) {
        unsigned int prev = 0u;
        #pragma unroll
        for (int j = 0; j < 16; ++j) {
            const unsigned int cur_u = bins[j * 128 + t];
            const float b = (float)((cur_u & 0xFFFFu) + (prev >> 16));
            prev = cur_u;
            s_local += b;
            slg = fmaf(b, __logf(b + 1e-6f), slg);
        }
    }

    const float2 sb = block_sum2_512(make_float2(s_local, slg), red);
    const float B = sb.x + EPS;
    if (t == 0) ent_partial[bid] = __logf(B) - sb.y * fast_rcp(B);
}

__global__ __launch_bounds__(64) void bq_ent_reduce(
    const float* __restrict__ part, float* __restrict__ out_ent)
{
    const int t = threadIdx.x;  // 64 threads, 1024 partials
    float v = 0.0f;
    #pragma unroll
    for (int i = 0; i < 16; ++i) v += part[t + i * 64];
    #pragma unroll
    for (int o = 32; o > 0; o >>= 1) v += __shfl_xor(v, o, 64);
    if (t == 0) out_ent[0] = v;
}

extern "C" void kernel_launch(void* const* d_in, const int* in_sizes, int n_in,
                              void* d_out, int out_size, void* d_ws, size_t ws_size,
                              hipStream_t stream) {
    const float* weight = (const float*)d_in[0];
    const float* wmin = (const float*)d_in[1];
    const float* wmax = (const float*)d_in[2];
    float* out = (float*)d_out;
    float* part = (float*)d_ws;  // 1024 floats of scratch

    bq_main_kernel<<<1024, 512, 0, stream>>>(weight, wmin, wmax, out, part);
    bq_ent_reduce<<<1, 64, 0, stream>>>(part, out + (out_size - 1));
}